// Round 11
// baseline (370.504 us; speedup 1.0000x reference)
//
#include <hip/hip_runtime.h>
#include <math.h>

// Problem constants (from reference setup_inputs).
constexpr int B_ = 2048;
constexpr int C_ = 9605;
constexpr int L_ = 8;
constexpr int TOPK_ = 16;
constexpr int CAPC_ = 384;     // candidate floats per row (~219 expected, +11 sigma)
constexpr float T0_ = 2.0f;    // candidate prefilter (16th largest ~2.95); guarded exact
constexpr int CS_ = 9632;      // bytes per lead-shifted code copy (2408 dwords)

__device__ __forceinline__ float sigm(float v) { return 1.0f / (1.0f + expf(-v)); }

// our_rank_loss: d = x2 - x1 + margin; s = sigmoid(5d); 2s when violated (d>0)
__device__ __forceinline__ float rank_loss(float x1, float x2) {
  float d = x2 - x1 + 0.05f;
  float s = 1.0f / (1.0f + expf(-5.0f * d));
  return (d > 0.0f) ? 2.0f * s : s;
}

// Order-preserving float->uint key (ascending) and inverse (all floats).
__device__ __forceinline__ unsigned int fkey(float v) {
  unsigned int u = __float_as_uint(v);
  return u ^ ((u & 0x80000000u) ? 0xFFFFFFFFu : 0x80000000u);
}
__device__ __forceinline__ float fkeyinv(unsigned int k) {
  unsigned int u = (k & 0x80000000u) ? (k ^ 0x80000000u) : ~k;
  return __uint_as_float(u);
}

// Per-lane prefix count over a 64-bit wave mask (bits below this lane).
__device__ __forceinline__ int mprefix(unsigned long long m) {
  return (int)__builtin_amdgcn_mbcnt_hi(
      (unsigned int)(m >> 32),
      __builtin_amdgcn_mbcnt_lo((unsigned int)m, 0u));
}

// Setup: FOUR lead-shifted packed code copies (copy ld, byte p = code of class
// p+ld; 0xFF pad) + init per-row tables.
__global__ void setup_kernel(const int* __restrict__ mask,
                             unsigned char* __restrict__ code4,
                             unsigned int* __restrict__ gslotG,
                             unsigned int* __restrict__ gtG,
                             unsigned int* __restrict__ gtnG,
                             int* __restrict__ cntG) {
  const int tid = blockIdx.x * 256 + threadIdx.x;  // grid 38*256 = 9728 threads
  if (tid < CS_ + 3) {
    unsigned char cd = 0xFF;
    if (tid < C_) {
#pragma unroll
      for (int l = L_ - 1; l >= 0; --l)
        if (mask[l * C_ + tid] != 0) cd = (unsigned char)l;
    }
#pragma unroll
    for (int ld = 0; ld < 4; ++ld) {
      int p = tid - ld;
      if (p >= 0 && p < CS_) code4[ld * CS_ + p] = cd;
    }
  }
  for (int i = tid; i < B_ * 8; i += 9728) gslotG[i] = 0x80000000u;  // key(+0.0)
  for (int i = tid; i < B_; i += 9728) { gtG[i] = 0u; gtnG[i] = 0u; cntG[i] = 0; }
}

// Barrier-free, LDS-free dense sweep. 3 x 2048 blocks; group g = bid>>11 owns
// ONE stream (0=x, 1=y, 2=yn). All per-element state lives in registers;
// wave-level aggregation uses ballots/shuffles; per-row tables get a handful
// of device atomics per wave per step. No __syncthreads anywhere -> the
// compiler may pipeline step k+1 loads under step k processing (bw_probe-like).
__global__ void __launch_bounds__(256, 8) wave_sweep(
    const float* __restrict__ x, const float* __restrict__ y,
    const float* __restrict__ yn, const unsigned char* __restrict__ code4,
    unsigned int* __restrict__ gslotG, unsigned int* __restrict__ gtG,
    unsigned int* __restrict__ gtnG, int* __restrict__ cntG,
    float* __restrict__ candG) {
  constexpr int NE = B_ * C_;            // 19,671,040 (divisible by 4)
  constexpr int NQ = NE / 4;             // 4,917,760 quads
  constexpr int TTQ = 2048 * 256;        // quads per group-step
  constexpr int NSTEP = (NQ + TTQ - 1) / TTQ;  // 10
  const int t = threadIdx.x;
  const int g = (int)blockIdx.x >> 11;   // 0=x, 1=y, 2=yn
  const int vb = (int)blockIdx.x & 2047;
  const int ln = t & 63;
  const float* src = (g == 0) ? x : ((g == 1) ? y : yn);

#pragma unroll 1
  for (int step = 0; step < NSTEP; ++step) {
    const int qw = step * TTQ + vb * 256 + (t & ~63);  // wave-uniform 1st quad
    if (qw >= NQ) continue;                            // wave-uniform skip
    const int q = qw + ln;
    const int efirst = qw << 2;
    const int rfirst = efirst / C_;
    int elast = efirst + 255; if (elast >= NE) elast = NE - 1;
    const bool single = (elast / C_) == rfirst;        // wave span in one row
    const bool act = (q < NQ);

    float4 V = make_float4(0.0f, 0.0f, 0.0f, 0.0f);
    int e0 = 0, row = rfirst, cc = 0;
    bool wrapq = false;
    unsigned int cw = 0u;
    if (act) {
      e0 = q << 2;
      V = *reinterpret_cast<const float4*>(src + e0);
      row = e0 / C_;
      cc = e0 - row * C_;
      wrapq = (cc + 3 >= C_);                          // quad spans two rows
      if (!wrapq)
        cw = *reinterpret_cast<const unsigned int*>(
            code4 + (size_t)(((cc & 3) * CS_) + (cc & ~3)));
    }
    const bool cok = act && !wrapq;

    if (g == 0) {
      // ---------------- x: group maxima + top-16 candidates ----------------
      if (cok) {
        const float xv[4] = {V.x, V.y, V.z, V.w};
#pragma unroll
        for (int k2 = 0; k2 < 4; ++k2) {
          unsigned int cd = (cw >> (8 * k2)) & 0xFFu;
          float xk = xv[k2];
          if (cd < 8u && xk > 0.0f) {
            unsigned int key = __float_as_uint(xk) | 0x80000000u;
            unsigned int cur = gslotG[row * 8 + (int)cd];  // racy prefilter:
            if (key > cur) atomicMax(&gslotG[row * 8 + (int)cd], key);  // stale
          }                                                // => smaller => safe
        }
      } else if (act) {  // wrap quad (1 per row boundary): exact per-element
        const float xv[4] = {V.x, V.y, V.z, V.w};
        int ccc = cc, rw = row;
#pragma unroll
        for (int k2 = 0; k2 < 4; ++k2) {
          unsigned int cd = code4[ccc];  // copy 0 = plain codes
          float xk = xv[k2];
          if (cd < 8u && xk > 0.0f)
            atomicMax(&gslotG[rw * 8 + (int)cd],
                      __float_as_uint(xk) | 0x80000000u);
          if (xk > T0_) {
            int p = atomicAdd(&cntG[rw], 1);
            if (p < CAPC_) candG[(size_t)rw * CAPC_ + p] = xk;
          }
          if (++ccc == C_) { ccc = 0; ++rw; }
        }
      }
      // Candidate capture for non-wrap lanes.
      if (single) {
        // Wave compaction: 4 ballots, one atomicAdd per wave, scatter stores.
        unsigned long long m0 = __ballot(cok && V.x > T0_);
        unsigned long long m1 = __ballot(cok && V.y > T0_);
        unsigned long long m2 = __ballot(cok && V.z > T0_);
        unsigned long long m3 = __ballot(cok && V.w > T0_);
        int n0 = __popcll(m0), n1 = __popcll(m1), n2 = __popcll(m2);
        int tot = n0 + n1 + n2 + __popcll(m3);
        if (tot) {  // wave-uniform
          int base = 0;
          if (ln == 0) base = atomicAdd(&cntG[rfirst], tot);
          base = __shfl(base, 0, 64);
          float* cr = candG + (size_t)rfirst * CAPC_;
          if (cok) {
            if (V.x > T0_) { int p = base + mprefix(m0); if (p < CAPC_) cr[p] = V.x; }
            if (V.y > T0_) { int p = base + n0 + mprefix(m1); if (p < CAPC_) cr[p] = V.y; }
            if (V.z > T0_) { int p = base + n0 + n1 + mprefix(m2); if (p < CAPC_) cr[p] = V.z; }
            if (V.w > T0_) { int p = base + n0 + n1 + n2 + mprefix(m3); if (p < CAPC_) cr[p] = V.w; }
          }
        }
      } else if (cok) {  // boundary wave (~2.7%): direct per-element push
        const float xv[4] = {V.x, V.y, V.z, V.w};
#pragma unroll
        for (int k2 = 0; k2 < 4; ++k2) {
          if (xv[k2] > T0_) {
            int p = atomicAdd(&cntG[row], 1);
            if (p < CAPC_) candG[(size_t)row * CAPC_ + p] = xv[k2];
          }
        }
      }
    } else {
      // ---------------- y / yn: label bits (positives ~0.15%) ----------------
      unsigned int b0 = 0u, b1 = 0u;
      if (cok) {
        unsigned int bb = 0u;
        if (V.x > 0.0f) { unsigned int cd = cw & 0xFFu;        if (cd < 8u) bb |= 1u << cd; }
        if (V.y > 0.0f) { unsigned int cd = (cw >> 8) & 0xFFu; if (cd < 8u) bb |= 1u << cd; }
        if (V.z > 0.0f) { unsigned int cd = (cw >> 16) & 0xFFu;if (cd < 8u) bb |= 1u << cd; }
        if (V.w > 0.0f) { unsigned int cd = cw >> 24;          if (cd < 8u) bb |= 1u << cd; }
        if (row == rfirst) b0 = bb; else b1 = bb;
      } else if (act) {  // wrap quad: per-element with per-element row
        const float xv[4] = {V.x, V.y, V.z, V.w};
        int ccc = cc, rw = row;
#pragma unroll
        for (int k2 = 0; k2 < 4; ++k2) {
          if (xv[k2] > 0.0f) {
            unsigned int cd = code4[ccc];
            if (cd < 8u) { if (rw == rfirst) b0 |= 1u << cd; else b1 |= 1u << cd; }
          }
          if (++ccc == C_) { ccc = 0; ++rw; }
        }
      }
      if (__any((int)(b0 | b1))) {  // wave-uniform skip when all zero (typical)
#pragma unroll
        for (int off = 32; off > 0; off >>= 1) {
          b0 |= __shfl_xor(b0, off, 64);
          b1 |= __shfl_xor(b1, off, 64);
        }
        unsigned int* dst = (g == 1) ? gtG : gtnG;
        if (ln == 0) {
          if (b0) atomicOr(&dst[rfirst], b0);
          if (b1) atomicOr(&dst[rfirst + 1], b1);
        }
      }
    }
  }
}

// Finish: one wave per row. All candidates are exactly the row's elements
// > T0 (no junk): cnt in [16, CAPC_] => buffer 16th-largest == row 16th-largest.
// Else exact wave-wide bisection over the row. Then the loss epilogue.
__global__ void finish_kernel(
    const float* __restrict__ x, const unsigned int* __restrict__ gslotG,
    const unsigned int* __restrict__ gtG, const unsigned int* __restrict__ gtnG,
    const int* __restrict__ cntG, const float* __restrict__ candG,
    float* __restrict__ loss) {
  const int r = blockIdx.x;
  const int t = threadIdx.x;  // 64 = one wave; no barriers needed
  const int cnt = cntG[r];
  float x16;
  if (cnt >= TOPK_ && cnt <= CAPC_) {
    const float* cf = candG + (size_t)r * CAPC_;
    unsigned int ku[CAPC_ / 64];  // 6 keys/lane, statically indexed
#pragma unroll
    for (int k = 0; k < CAPC_ / 64; ++k) {
      int i = t + (k << 6);
      ku[k] = (i < cnt) ? fkey(cf[i]) : 0u;
    }
    unsigned int lo = 0u, hi = 0xFFFFFFFFu;
#pragma unroll 1
    for (int it = 0; it < 32 && lo < hi; ++it) {
      unsigned int mid = lo + ((hi - lo) >> 1) + 1u;
      int c16 = 0;
#pragma unroll
      for (int k = 0; k < CAPC_ / 64; ++k) c16 += (ku[k] >= mid) ? 1 : 0;
#pragma unroll
      for (int off = 32; off > 0; off >>= 1) c16 += __shfl_xor(c16, off, 64);
      if (c16 >= TOPK_) lo = mid; else hi = mid - 1u;
    }
    x16 = fkeyinv(lo);
  } else {
    // Fallback (statistically never): exact wave-wide bisection over the row.
    const float* xr = x + (size_t)r * C_;
    unsigned int lo = 0u, hi = 0xFFFFFFFFu;
#pragma unroll 1
    for (int it = 0; it < 32 && lo < hi; ++it) {
      unsigned int mid = lo + ((hi - lo) >> 1) + 1u;
      int cl = 0;
      for (int c = t; c < C_; c += 64) cl += (fkey(xr[c]) >= mid) ? 1 : 0;
#pragma unroll
      for (int off = 32; off > 0; off >>= 1) cl += __shfl_xor(cl, off, 64);
      if (cl >= TOPK_) lo = mid; else hi = mid - 1u;
    }
    x16 = fkeyinv(lo);
  }
  if (t == 0) {
    float thres = fmaxf(sigm(x16), 0.3f);
    unsigned int gtb = gtG[r], gnb = gtnG[r];
    float caseB = 0.0f, unio = -INFINITY, negmax = -INFINITY;
#pragma unroll
    for (int l = 0; l < L_; ++l) {
      float gm = __uint_as_float(gslotG[r * 8 + l] ^ 0x80000000u);  // decode key
      float g = sigm(gm);
      unio = fmaxf(unio, g);
      caseB += ((gtb >> l) & 1u) ? rank_loss(g, thres) : rank_loss(thres, g);
      if ((gnb >> l) & 1u) negmax = fmaxf(negmax, g);
    }
    float negscore = (gnb != 0u) ? negmax : 0.0f;
    float caseA = 0.5f * rank_loss(thres, unio) + 0.5f * rank_loss(thres, negscore);
    loss[r] = (gtb != 0u) ? caseB : caseA;
  }
}

// Deterministic mean of the 2048 per-row losses.
__global__ void mean_kernel(const float* __restrict__ loss, float* __restrict__ out) {
  const int t = threadIdx.x;
  float s = 0.0f;
  for (int i = t; i < B_; i += 256) s += loss[i];
#pragma unroll
  for (int off = 32; off > 0; off >>= 1) s += __shfl_xor(s, off, 64);
  __shared__ float part[4];
  if ((t & 63) == 0) part[t >> 6] = s;
  __syncthreads();
  if (t == 0) out[0] = (part[0] + part[1] + part[2] + part[3]) * (1.0f / (float)B_);
}

extern "C" void kernel_launch(void* const* d_in, const int* in_sizes, int n_in,
                              void* d_out, int out_size, void* d_ws, size_t ws_size,
                              hipStream_t stream) {
  const float* x = (const float*)d_in[0];
  const float* y = (const float*)d_in[1];
  const float* yn = (const float*)d_in[2];
  const int* mask = (const int*)d_in[3];  // bool promoted to int32 by harness

  // Workspace layout, ~3.28 MB total (ws_size proven >= 4.33 MB, rounds 4-10).
  constexpr size_t OFF_LOSS = 0;                              // 2048 f32
  constexpr size_t OFF_CODE4 = 8192;                          // 4*CS_ bytes
  constexpr size_t OFF_GSLOT = OFF_CODE4 + 4 * CS_;           // 2048*8 u32
  constexpr size_t OFF_GT = OFF_GSLOT + B_ * 8 * 4;           // 2048 u32
  constexpr size_t OFF_GTN = OFF_GT + B_ * 4;                 // 2048 u32
  constexpr size_t OFF_CNT = OFF_GTN + B_ * 4;                // 2048 i32
  constexpr size_t OFF_CAND = OFF_CNT + B_ * 4;               // 2048*CAPC_ f32

  float* loss = (float*)((char*)d_ws + OFF_LOSS);
  unsigned char* code4 = (unsigned char*)d_ws + OFF_CODE4;
  unsigned int* gslotG = (unsigned int*)((char*)d_ws + OFF_GSLOT);
  unsigned int* gtG = (unsigned int*)((char*)d_ws + OFF_GT);
  unsigned int* gtnG = (unsigned int*)((char*)d_ws + OFF_GTN);
  int* cntG = (int*)((char*)d_ws + OFF_CNT);
  float* candG = (float*)((char*)d_ws + OFF_CAND);

  hipLaunchKernelGGL(setup_kernel, dim3(38), dim3(256), 0, stream,
                     mask, code4, gslotG, gtG, gtnG, cntG);
  hipLaunchKernelGGL(wave_sweep, dim3(3 * 2048), dim3(256), 0, stream,
                     x, y, yn, code4, gslotG, gtG, gtnG, cntG, candG);
  hipLaunchKernelGGL(finish_kernel, dim3(2048), dim3(64), 0, stream,
                     x, gslotG, gtG, gtnG, cntG, candG, loss);
  hipLaunchKernelGGL(mean_kernel, dim3(1), dim3(256), 0, stream,
                     loss, (float*)d_out);
}